// Round 2
// baseline (51.424 us; speedup 1.0000x reference)
//
#include <hip/hip_runtime.h>

namespace {
constexpr int kFrame = 80;     // FRAME_SIZE
constexpr int kRad   = 2;      // RADIUS
constexpr int kW     = 5;      // 2*RADIUS+1
constexpr int kB     = 64;
constexpr int kF     = 4000;
constexpr int kN     = kFrame * kF;        // 320000 samples per batch row

constexpr int FPB     = 128;               // frames per block
constexpr int BPB     = (kF + FPB - 1) / FPB;  // 32 blocks per batch
constexpr int HALO_LO = 304;               // >= PITCH_MAX(300)-p_min... covers lbase >= 4; mult of 4
constexpr int HALO_HI = 84;                // covers +RADIUS past frame end; mult of 4
constexpr int LN      = FPB * kFrame + HALO_LO + HALO_HI;   // 10628 logical floats
constexpr int LPHYS   = LN + 4 * ((LN + 31) / 32);          // 11960 padded floats (47.8 KB)
constexpr int NITER   = (LN / 4 + 255) / 256;               // 11 staging iters
}

// Bank-deconflict remap: +4 pad words per 32. Preserves contiguity AND 16B
// alignment of any aligned quad (i%4==0 -> i%32<=28 -> no group crossing).
__device__ __forceinline__ int phys(int i) { return i + ((i >> 5) << 2); }

template <bool SAFE>
__device__ __forceinline__ void stage(const float* __restrict__ xb, float* lds,
                                      int o, int tid) {
#pragma unroll
    for (int k = 0; k < NITER; ++k) {
        int i4 = (k * 256 + tid) * 4;
        if (i4 < LN) {
            int p0 = phys(i4);
            if constexpr (SAFE) {
                float4 v = *reinterpret_cast<const float4*>(xb + o + i4);
                *reinterpret_cast<float4*>(&lds[p0]) = v;   // 16B-aligned by construction
            } else {
#pragma unroll
                for (int e = 0; e < 4; ++e) {
                    int g = o + i4 + e;
                    // JAX pad semantics: g<0 -> 0; g>=N -> x[N-1]
                    float v = 0.0f;
                    if (g >= 0) v = xb[g < kN ? g : (kN - 1)];
                    lds[p0 + e] = v;
                }
            }
        }
    }
}

__global__ __launch_bounds__(256)
void pitch_acorr_kernel(const float* __restrict__ x,
                        const int* __restrict__ periods,
                        float* __restrict__ out) {
    __shared__ float lds[LPHYS];

    const int bid = blockIdx.x;
    const int b   = bid / BPB;
    const int blk = bid - b * BPB;
    const int f0  = blk * FPB;
    const int nf  = min(FPB, kF - f0);
    const int tid = threadIdx.x;
    const float* xb = x + (long long)b * kN;
    const int o = f0 * kFrame - HALO_LO;   // global index of lds logical 0 (mult of 4)

    const bool safe = (o >= 0) && (o + LN <= kN);   // block-uniform
    if (safe) stage<true >(xb, lds, o, tid);
    else      stage<false>(xb, lds, o, tid);
    __syncthreads();

    const int fl = tid >> 1;     // local frame
    const int h  = tid & 1;      // half: 0 -> t=0..39, 1 -> t=40..79
    if (fl < nf) {
        const int p = periods[b * kF + f0 + fl];
        const int fbase = fl * kFrame + HALO_LO + h * 40;  // logical idx of first frame sample
        const int lbase = fbase - p - kRad;                 // first lag logical idx (>= 4)

        float w0 = lds[phys(lbase + 0)];
        float w1 = lds[phys(lbase + 1)];
        float w2 = lds[phys(lbase + 2)];
        float w3 = lds[phys(lbase + 3)];
        float d0 = 0.f, d1 = 0.f, d2 = 0.f, d3 = 0.f, d4 = 0.f;
        float l0 = 0.f, l1 = 0.f, l2 = 0.f, l3 = 0.f, l4 = 0.f;
        float fn = 0.f;

#define ACORR_STEP(FT, T)                                                     \
    {                                                                         \
        float w4 = lds[phys(lbase + (T) + 4)];                                \
        float ft = (FT);                                                      \
        fn += ft * ft;                                                        \
        d0 += ft * w0; d1 += ft * w1; d2 += ft * w2; d3 += ft * w3;           \
        d4 += ft * w4;                                                        \
        l0 += w0 * w0; l1 += w1 * w1; l2 += w2 * w2; l3 += w3 * w3;           \
        l4 += w4 * w4;                                                        \
        w0 = w1; w1 = w2; w2 = w3; w3 = w4;                                   \
    }

#pragma unroll
        for (int t4 = 0; t4 < 40; t4 += 4) {
            const float4 fr = *reinterpret_cast<const float4*>(&lds[phys(fbase + t4)]);
            ACORR_STEP(fr.x, t4 + 0);
            ACORR_STEP(fr.y, t4 + 1);
            ACORR_STEP(fr.z, t4 + 2);
            ACORR_STEP(fr.w, t4 + 3);
        }
#undef ACORR_STEP

        // pair-reduce (lanes 2t / 2t+1 are in the same wave)
        d0 += __shfl_xor(d0, 1); d1 += __shfl_xor(d1, 1); d2 += __shfl_xor(d2, 1);
        d3 += __shfl_xor(d3, 1); d4 += __shfl_xor(d4, 1);
        l0 += __shfl_xor(l0, 1); l1 += __shfl_xor(l1, 1); l2 += __shfl_xor(l2, 1);
        l3 += __shfl_xor(l3, 1); l4 += __shfl_xor(l4, 1);
        fn += __shfl_xor(fn, 1);

        if (h == 0) {
            float* op = out + (long long)(b * kF + f0 + fl) * kW;
            op[0] = d0 * rsqrtf(fn * l0 + 1e-9f);
            op[1] = d1 * rsqrtf(fn * l1 + 1e-9f);
            op[2] = d2 * rsqrtf(fn * l2 + 1e-9f);
            op[3] = d3 * rsqrtf(fn * l3 + 1e-9f);
            op[4] = d4 * rsqrtf(fn * l4 + 1e-9f);
        }
    }
}

extern "C" void kernel_launch(void* const* d_in, const int* in_sizes, int n_in,
                              void* d_out, int out_size, void* d_ws, size_t ws_size,
                              hipStream_t stream) {
    const float* x       = (const float*)d_in[0];
    const int*   periods = (const int*)d_in[1];
    float*       out     = (float*)d_out;

    const int grid = kB * BPB;   // 2048 blocks, one per (batch, 128-frame chunk)
    pitch_acorr_kernel<<<grid, 256, 0, stream>>>(x, periods, out);
}

// Round 3
// 43.360 us; speedup vs baseline: 1.1860x; 1.1860x over previous
//
#include <hip/hip_runtime.h>

namespace {
constexpr int kFrame = 80;     // FRAME_SIZE
constexpr int kRad   = 2;      // RADIUS
constexpr int kW     = 5;      // 2*RADIUS+1
constexpr int kB     = 64;
constexpr int kF     = 4000;
constexpr int kN     = kFrame * kF;        // 320000 samples per batch row

constexpr int FPB     = 64;                // frames per block (4 threads/frame)
constexpr int BPB     = (kF + FPB - 1) / FPB;  // 63 blocks per batch
constexpr int HALO_LO = 304;               // covers lbase >= 4 (p <= 298); mult of 16
constexpr int HALO_HI = 84;
constexpr int LN      = FPB * kFrame + HALO_LO + HALO_HI;   // 5508 logical floats
constexpr int LPHYS   = LN + 4 * ((LN + 31) / 32);          // 6200 floats (24.8 KB)
constexpr int NITER   = (LN / 4 + 255) / 256;               // 6 staging iters
}

// Bank-deconflict remap: +4 pad words per 32. Preserves contiguity AND 16B
// alignment of any aligned quad.
__device__ __forceinline__ int phys(int i) { return i + ((i >> 5) << 2); }

template <bool SAFE>
__device__ __forceinline__ void stage(const float* __restrict__ xb, float* lds,
                                      int o, int tid) {
#pragma unroll
    for (int k = 0; k < NITER; ++k) {
        int i4 = (k * 256 + tid) * 4;
        if (i4 < LN) {
            int p0 = phys(i4);
            if constexpr (SAFE) {
                *reinterpret_cast<float4*>(&lds[p0]) =
                    *reinterpret_cast<const float4*>(xb + o + i4);
            } else {
#pragma unroll
                for (int e = 0; e < 4; ++e) {
                    int g = o + i4 + e;
                    // JAX pad semantics: g<0 -> 0; g>=N -> x[N-1]
                    float v = 0.0f;
                    if (g >= 0) v = xb[g < kN ? g : (kN - 1)];
                    lds[p0 + e] = v;
                }
            }
        }
    }
}

__global__ __launch_bounds__(256, 6)
void pitch_acorr_kernel(const float* __restrict__ x,
                        const int* __restrict__ periods,
                        float* __restrict__ out) {
    __shared__ float lds[LPHYS];

    const int bid = blockIdx.x;
    const int b   = bid / BPB;
    const int blk = bid - b * BPB;
    const int f0  = blk * FPB;
    const int nf  = min(FPB, kF - f0);
    const int tid = threadIdx.x;
    const float* xb = x + (long long)b * kN;
    const int o = f0 * kFrame - HALO_LO;   // global idx of lds logical 0 (16B-aligned)

    const bool safe = (o >= 0) && (o + LN <= kN);   // block-uniform
    if (safe) stage<true >(xb, lds, o, tid);
    else      stage<false>(xb, lds, o, tid);
    __syncthreads();

    const int fl = tid >> 2;     // local frame
    const int q  = tid & 3;      // quarter: samples [20q, 20q+20)
    const int h  = q * 20;
    if (fl >= nf) return;        // no barriers below

    const int p     = periods[b * kF + f0 + fl];
    const int fbase = fl * kFrame + HALO_LO;   // logical idx of frame start
    const int lbase = fbase - p - kRad;        // >= 4 always (p <= 298)
    const int s     = lbase & 3;               // quad misalignment, 0..3
    const int A0    = lbase - s;               // 16B-aligned lag base

    const int fst = fbase + h;   // 5 frame quads from here
    const int gst = A0 + h;      // 7 lag quads from here (need g[h .. h+26])

    // d_k = D[k+s], l_k = E[k+s]:  D_j = sum_t f[t]*g[t+j], E_j = sum_t g[t+j]^2
    float D[8] = {0, 0, 0, 0, 0, 0, 0, 0};
    float fn = 0.f, E0 = 0.f;
    float clo[7], chi[7];

    float4 G0 = *reinterpret_cast<const float4*>(&lds[phys(gst)]);
    float4 G1 = *reinterpret_cast<const float4*>(&lds[phys(gst + 4)]);

#pragma unroll
    for (int u = 0; u < 5; ++u) {
        float4 G2 = *reinterpret_cast<const float4*>(&lds[phys(gst + 4 * u + 8)]);
        float4 Fq = *reinterpret_cast<const float4*>(&lds[phys(fst + 4 * u)]);
        float g[12] = {G0.x, G0.y, G0.z, G0.w, G1.x, G1.y, G1.z, G1.w,
                       G2.x, G2.y, G2.z, G2.w};
        float f[4]  = {Fq.x, Fq.y, Fq.z, Fq.w};
#pragma unroll
        for (int i = 0; i < 4; ++i) {
            fn += f[i] * f[i];
#pragma unroll
            for (int j = 0; j < 8; ++j) D[j] += f[i] * g[i + j];
        }
        E0 += g[0]*g[0] + g[1]*g[1] + g[2]*g[2] + g[3]*g[3];
        if (u == 0) {   // g[h .. h+6]
            clo[0]=g[0]; clo[1]=g[1]; clo[2]=g[2]; clo[3]=g[3];
            clo[4]=g[4]; clo[5]=g[5]; clo[6]=g[6];
        }
        if (u == 4) {   // g[h+20 .. h+26]  (G1=quad5, G2=quad6 here)
            chi[0]=g[4]; chi[1]=g[5]; chi[2]=g[6]; chi[3]=g[7];
            chi[4]=g[8]; chi[5]=g[9]; chi[6]=g[10];
        }
        G0 = G1; G1 = G2;
    }

    // sliding energy windows: E_{j+1} = E_j - g[h+j]^2 + g[h+20+j]^2
    float E[8];
    E[0] = E0;
#pragma unroll
    for (int j = 0; j < 7; ++j) E[j + 1] = E[j] + (chi[j]*chi[j] - clo[j]*clo[j]);

    // select by s (2-bit cndmask tree), then butterfly-reduce over the 4 quarters
    float dsel[5], esel[5];
    const bool s1 = (s & 1) != 0, s2 = (s & 2) != 0;
#pragma unroll
    for (int k = 0; k < 5; ++k) {
        float da = s1 ? D[k + 1] : D[k];
        float db = s1 ? D[k + 3] : D[k + 2];
        dsel[k] = s2 ? db : da;
        float ea = s1 ? E[k + 1] : E[k];
        float eb = s1 ? E[k + 3] : E[k + 2];
        esel[k] = s2 ? eb : ea;
    }

    fn += __shfl_xor(fn, 1); fn += __shfl_xor(fn, 2);
#pragma unroll
    for (int k = 0; k < 5; ++k) {
        dsel[k] += __shfl_xor(dsel[k], 1); dsel[k] += __shfl_xor(dsel[k], 2);
        esel[k] += __shfl_xor(esel[k], 1); esel[k] += __shfl_xor(esel[k], 2);
    }

    if (q == 0) {
        float* op = out + (long long)(b * kF + f0 + fl) * kW;
#pragma unroll
        for (int k = 0; k < 5; ++k)
            op[k] = dsel[k] * rsqrtf(fn * esel[k] + 1e-9f);
    }
}

extern "C" void kernel_launch(void* const* d_in, const int* in_sizes, int n_in,
                              void* d_out, int out_size, void* d_ws, size_t ws_size,
                              hipStream_t stream) {
    const float* x       = (const float*)d_in[0];
    const int*   periods = (const int*)d_in[1];
    float*       out     = (float*)d_out;

    const int grid = kB * BPB;   // 4032 blocks, one per (batch, 64-frame chunk)
    pitch_acorr_kernel<<<grid, 256, 0, stream>>>(x, periods, out);
}

// Round 4
// 43.242 us; speedup vs baseline: 1.1892x; 1.0027x over previous
//
#include <hip/hip_runtime.h>

namespace {
constexpr int kFrame = 80;     // FRAME_SIZE
constexpr int kRad   = 2;      // RADIUS
constexpr int kW     = 5;      // 2*RADIUS+1
constexpr int kB     = 64;
constexpr int kF     = 4000;
constexpr int kN     = kFrame * kF;        // 320000 samples per batch row

constexpr int FPB     = 64;                // frames per block (4 threads/frame)
constexpr int BPB     = (kF + FPB - 1) / FPB;  // 63 blocks per batch
constexpr int HALO_LO = 304;               // covers lbase >= 4 (p <= 298); mult of 16
constexpr int HALO_HI = 84;
constexpr int LN      = FPB * kFrame + HALO_LO + HALO_HI;   // 5508 logical floats
constexpr int LPHYS   = LN + 4 * ((LN + 31) / 32);          // 6200 floats (24.8 KB)
constexpr int NITER   = (LN / 4 + 255) / 256;               // 6 staging iters
}

// Bank-deconflict remap: +4 pad words per 32. Preserves contiguity AND 16B
// alignment of any aligned quad.
__device__ __forceinline__ int phys(int i) { return i + ((i >> 5) << 2); }

template <bool SAFE>
__device__ __forceinline__ void stage(const float* __restrict__ xb, float* lds,
                                      int o, int tid) {
#pragma unroll
    for (int k = 0; k < NITER; ++k) {
        int i4 = (k * 256 + tid) * 4;
        if (i4 < LN) {
            int p0 = phys(i4);
            if constexpr (SAFE) {
                *reinterpret_cast<float4*>(&lds[p0]) =
                    *reinterpret_cast<const float4*>(xb + o + i4);
            } else {
#pragma unroll
                for (int e = 0; e < 4; ++e) {
                    int g = o + i4 + e;
                    // JAX pad semantics: g<0 -> 0; g>=N -> x[N-1]
                    float v = 0.0f;
                    if (g >= 0) v = xb[g < kN ? g : (kN - 1)];
                    lds[p0 + e] = v;
                }
            }
        }
    }
}

// NOTE: plain launch_bounds. (256,6) let the VGPR heuristic cap at 40 regs ->
// massive scratch spill (WRITE_SIZE 5MB -> 69MB, R3). ~90 VGPR is fine: LDS
// (24.8KB) caps occupancy at 6 blocks/CU anyway.
__global__ __launch_bounds__(256)
void pitch_acorr_kernel(const float* __restrict__ x,
                        const int* __restrict__ periods,
                        float* __restrict__ out) {
    __shared__ float lds[LPHYS];

    const int bid = blockIdx.x;
    const int b   = bid / BPB;
    const int blk = bid - b * BPB;
    const int f0  = blk * FPB;
    const int nf  = min(FPB, kF - f0);
    const int tid = threadIdx.x;
    const float* xb = x + (long long)b * kN;
    const int o = f0 * kFrame - HALO_LO;   // global idx of lds logical 0 (16B-aligned)

    const int fl = tid >> 2;     // local frame
    const int q  = tid & 3;      // quarter: samples [20q, 20q+20)
    const int h  = q * 20;

    // Prefetch period before staging so its latency hides under the copy.
    int p = 0;
    if (fl < nf) p = periods[b * kF + f0 + fl];

    const bool safe = (o >= 0) && (o + LN <= kN);   // block-uniform
    if (safe) stage<true >(xb, lds, o, tid);
    else      stage<false>(xb, lds, o, tid);
    __syncthreads();

    if (fl >= nf) return;        // no barriers below

    const int fbase = fl * kFrame + HALO_LO;   // logical idx of frame start
    const int lbase = fbase - p - kRad;        // >= 4 always (p <= 298)
    const int s     = lbase & 3;               // quad misalignment, 0..3
    const int A0    = lbase - s;               // 16B-aligned lag base

    const int fst = fbase + h;   // 5 frame quads from here
    const int gst = A0 + h;      // 7 lag quads from here (need g[h .. h+26])

    // d_k = D[k+s], l_k = E[k+s]:  D_j = sum_t f[t]*g[t+j], E_j = sum_t g[t+j]^2
    float D[8] = {0, 0, 0, 0, 0, 0, 0, 0};
    float fn = 0.f, E0 = 0.f;
    float clo[7], chi[7];

    float4 G0 = *reinterpret_cast<const float4*>(&lds[phys(gst)]);
    float4 G1 = *reinterpret_cast<const float4*>(&lds[phys(gst + 4)]);

#pragma unroll
    for (int u = 0; u < 5; ++u) {
        float4 G2 = *reinterpret_cast<const float4*>(&lds[phys(gst + 4 * u + 8)]);
        float4 Fq = *reinterpret_cast<const float4*>(&lds[phys(fst + 4 * u)]);
        float g[12] = {G0.x, G0.y, G0.z, G0.w, G1.x, G1.y, G1.z, G1.w,
                       G2.x, G2.y, G2.z, G2.w};
        float f[4]  = {Fq.x, Fq.y, Fq.z, Fq.w};
#pragma unroll
        for (int i = 0; i < 4; ++i) {
            fn += f[i] * f[i];
#pragma unroll
            for (int j = 0; j < 8; ++j) D[j] += f[i] * g[i + j];
        }
        E0 += g[0]*g[0] + g[1]*g[1] + g[2]*g[2] + g[3]*g[3];
        if (u == 0) {   // g[h .. h+6]
            clo[0]=g[0]; clo[1]=g[1]; clo[2]=g[2]; clo[3]=g[3];
            clo[4]=g[4]; clo[5]=g[5]; clo[6]=g[6];
        }
        if (u == 4) {   // g[h+20 .. h+26]  (G1=quad5, G2=quad6 here)
            chi[0]=g[4]; chi[1]=g[5]; chi[2]=g[6]; chi[3]=g[7];
            chi[4]=g[8]; chi[5]=g[9]; chi[6]=g[10];
        }
        G0 = G1; G1 = G2;
    }

    // sliding energy windows: E_{j+1} = E_j - g[h+j]^2 + g[h+20+j]^2
    float E[8];
    E[0] = E0;
#pragma unroll
    for (int j = 0; j < 7; ++j) E[j + 1] = E[j] + (chi[j]*chi[j] - clo[j]*clo[j]);

    // select by s (2-bit cndmask tree), then butterfly-reduce over the 4 quarters
    float dsel[5], esel[5];
    const bool s1 = (s & 1) != 0, s2 = (s & 2) != 0;
#pragma unroll
    for (int k = 0; k < 5; ++k) {
        float da = s1 ? D[k + 1] : D[k];
        float db = s1 ? D[k + 3] : D[k + 2];
        dsel[k] = s2 ? db : da;
        float ea = s1 ? E[k + 1] : E[k];
        float eb = s1 ? E[k + 3] : E[k + 2];
        esel[k] = s2 ? eb : ea;
    }

    fn += __shfl_xor(fn, 1); fn += __shfl_xor(fn, 2);
#pragma unroll
    for (int k = 0; k < 5; ++k) {
        dsel[k] += __shfl_xor(dsel[k], 1); dsel[k] += __shfl_xor(dsel[k], 2);
        esel[k] += __shfl_xor(esel[k], 1); esel[k] += __shfl_xor(esel[k], 2);
    }

    if (q == 0) {
        float* op = out + (long long)(b * kF + f0 + fl) * kW;
#pragma unroll
        for (int k = 0; k < 5; ++k)
            op[k] = dsel[k] * rsqrtf(fn * esel[k] + 1e-9f);
    }
}

extern "C" void kernel_launch(void* const* d_in, const int* in_sizes, int n_in,
                              void* d_out, int out_size, void* d_ws, size_t ws_size,
                              hipStream_t stream) {
    const float* x       = (const float*)d_in[0];
    const int*   periods = (const int*)d_in[1];
    float*       out     = (float*)d_out;

    const int grid = kB * BPB;   // 4032 blocks, one per (batch, 64-frame chunk)
    pitch_acorr_kernel<<<grid, 256, 0, stream>>>(x, periods, out);
}

// Round 5
// 27.489 us; speedup vs baseline: 1.8707x; 1.5731x over previous
//
#include <hip/hip_runtime.h>

namespace {
constexpr int kFrame = 80;     // FRAME_SIZE
constexpr int kRad   = 2;      // RADIUS
constexpr int kW     = 5;      // 2*RADIUS+1
constexpr int kB     = 64;
constexpr int kF     = 4000;
constexpr int kN     = kFrame * kF;        // 320000 samples per batch row

constexpr int FPB     = 64;                // frames per block (4 threads/frame)
constexpr int BPB     = (kF + FPB - 1) / FPB;  // 63 blocks per batch
constexpr int HALO_LO = 304;               // covers lbase >= 4 (p <= 298); mult of 16
constexpr int HALO_HI = 84;
constexpr int LN      = FPB * kFrame + HALO_LO + HALO_HI;   // 5508 logical floats
constexpr int LPHYS   = LN + 4 * ((LN + 31) / 32);          // 6200 floats (24.8 KB)
constexpr int NITER   = (LN / 4 + 255) / 256;               // 6 staging iters
}

// Bank-deconflict remap: +4 pad words per 32. Preserves contiguity AND 16B
// alignment of any aligned quad.
__device__ __forceinline__ int phys(int i) { return i + ((i >> 5) << 2); }

template <bool SAFE>
__device__ __forceinline__ void stage(const float* __restrict__ xb, float* lds,
                                      int o, int tid) {
#pragma unroll
    for (int k = 0; k < NITER; ++k) {
        int i4 = (k * 256 + tid) * 4;
        if (i4 < LN) {
            int p0 = phys(i4);
            if constexpr (SAFE) {
                *reinterpret_cast<float4*>(&lds[p0]) =
                    *reinterpret_cast<const float4*>(xb + o + i4);
            } else {
#pragma unroll
                for (int e = 0; e < 4; ++e) {
                    int g = o + i4 + e;
                    // JAX pad semantics: g<0 -> 0; g>=N -> x[N-1]
                    float v = 0.0f;
                    if (g >= 0) v = xb[g < kN ? g : (kN - 1)];
                    lds[p0 + e] = v;
                }
            }
        }
    }
}

// (256,4): allocator must sustain 4 waves/EU -> VGPR cap 128. R3/R4 showed the
// default heuristic memory-homes the compute arrays (VGPR=40, 64MB scratch
// writes); this version is fully scalarized so nothing CAN go to scratch.
__global__ __launch_bounds__(256, 4)
void pitch_acorr_kernel(const float* __restrict__ x,
                        const int* __restrict__ periods,
                        float* __restrict__ out) {
    __shared__ float lds[LPHYS];

    const int bid = blockIdx.x;
    const int b   = bid / BPB;
    const int blk = bid - b * BPB;
    const int f0  = blk * FPB;
    const int nf  = min(FPB, kF - f0);
    const int tid = threadIdx.x;
    const float* xb = x + (long long)b * kN;
    const int o = f0 * kFrame - HALO_LO;   // global idx of lds logical 0 (16B-aligned)

    const int fl = tid >> 2;     // local frame
    const int q  = tid & 3;      // quarter: samples [20q, 20q+20)
    const int h  = q * 20;

    // Prefetch period before staging so its latency hides under the copy.
    int p = 0;
    if (fl < nf) p = periods[b * kF + f0 + fl];

    const bool safe = (o >= 0) && (o + LN <= kN);   // block-uniform
    if (safe) stage<true >(xb, lds, o, tid);
    else      stage<false>(xb, lds, o, tid);
    __syncthreads();

    if (fl >= nf) return;        // no barriers below

    const int fbase = fl * kFrame + HALO_LO;   // logical idx of frame start
    const int lbase = fbase - p - kRad;        // >= 4 always (p <= 298)
    const int s     = lbase & 3;               // quad misalignment, 0..3
    const int A0    = lbase - s;               // 16B-aligned lag base

    const int fst = fbase + h;   // frame samples t=h..h+19 from here
    const int gst = A0 + h;      // lag window g[0..26] from here

#define LD4(i) (*reinterpret_cast<const float4*>(&lds[phys(i)]))
    // Issue all 12 ds_read_b128 upfront (no dependent chain).
    const float4 Ga = LD4(gst +  0), Gb = LD4(gst +  4), Gc = LD4(gst +  8),
                 Gd = LD4(gst + 12), Ge = LD4(gst + 16), Gf = LD4(gst + 20),
                 Gg = LD4(gst + 24);
    const float4 Fa = LD4(fst +  0), Fb = LD4(fst +  4), Fc = LD4(fst +  8),
                 Fd = LD4(fst + 12), Fe = LD4(fst + 16);
#undef LD4

    const float g0 = Ga.x, g1 = Ga.y, g2 = Ga.z, g3 = Ga.w,
                g4 = Gb.x, g5 = Gb.y, g6 = Gb.z, g7 = Gb.w,
                g8 = Gc.x, g9 = Gc.y, g10 = Gc.z, g11 = Gc.w,
                g12 = Gd.x, g13 = Gd.y, g14 = Gd.z, g15 = Gd.w,
                g16 = Ge.x, g17 = Ge.y, g18 = Ge.z, g19 = Ge.w,
                g20 = Gf.x, g21 = Gf.y, g22 = Gf.z, g23 = Gf.w,
                g24 = Gg.x, g25 = Gg.y, g26 = Gg.z;
    const float f0_ = Fa.x, f1 = Fa.y, f2 = Fa.z, f3 = Fa.w,
                f4 = Fb.x, f5 = Fb.y, f6 = Fb.z, f7 = Fb.w,
                f8 = Fc.x, f9 = Fc.y, f10 = Fc.z, f11 = Fc.w,
                f12 = Fd.x, f13 = Fd.y, f14 = Fd.z, f15 = Fd.w,
                f16 = Fe.x, f17 = Fe.y, f18 = Fe.z, f19 = Fe.w;

    float fn = f0_*f0_ + f1*f1 + f2*f2 + f3*f3 + f4*f4 + f5*f5 + f6*f6 + f7*f7
             + f8*f8 + f9*f9 + f10*f10 + f11*f11 + f12*f12 + f13*f13 + f14*f14
             + f15*f15 + f16*f16 + f17*f17 + f18*f18 + f19*f19;

    // D_j = sum_t f_t * g_{t+j};  d_k = D_{k+s}
    const float D0 = f0_*g0 + f1*g1 + f2*g2 + f3*g3 + f4*g4 + f5*g5 + f6*g6
                   + f7*g7 + f8*g8 + f9*g9 + f10*g10 + f11*g11 + f12*g12
                   + f13*g13 + f14*g14 + f15*g15 + f16*g16 + f17*g17 + f18*g18
                   + f19*g19;
    const float D1 = f0_*g1 + f1*g2 + f2*g3 + f3*g4 + f4*g5 + f5*g6 + f6*g7
                   + f7*g8 + f8*g9 + f9*g10 + f10*g11 + f11*g12 + f12*g13
                   + f13*g14 + f14*g15 + f15*g16 + f16*g17 + f17*g18 + f18*g19
                   + f19*g20;
    const float D2 = f0_*g2 + f1*g3 + f2*g4 + f3*g5 + f4*g6 + f5*g7 + f6*g8
                   + f7*g9 + f8*g10 + f9*g11 + f10*g12 + f11*g13 + f12*g14
                   + f13*g15 + f14*g16 + f15*g17 + f16*g18 + f17*g19 + f18*g20
                   + f19*g21;
    const float D3 = f0_*g3 + f1*g4 + f2*g5 + f3*g6 + f4*g7 + f5*g8 + f6*g9
                   + f7*g10 + f8*g11 + f9*g12 + f10*g13 + f11*g14 + f12*g15
                   + f13*g16 + f14*g17 + f15*g18 + f16*g19 + f17*g20 + f18*g21
                   + f19*g22;
    const float D4 = f0_*g4 + f1*g5 + f2*g6 + f3*g7 + f4*g8 + f5*g9 + f6*g10
                   + f7*g11 + f8*g12 + f9*g13 + f10*g14 + f11*g15 + f12*g16
                   + f13*g17 + f14*g18 + f15*g19 + f16*g20 + f17*g21 + f18*g22
                   + f19*g23;
    const float D5 = f0_*g5 + f1*g6 + f2*g7 + f3*g8 + f4*g9 + f5*g10 + f6*g11
                   + f7*g12 + f8*g13 + f9*g14 + f10*g15 + f11*g16 + f12*g17
                   + f13*g18 + f14*g19 + f15*g20 + f16*g21 + f17*g22 + f18*g23
                   + f19*g24;
    const float D6 = f0_*g6 + f1*g7 + f2*g8 + f3*g9 + f4*g10 + f5*g11 + f6*g12
                   + f7*g13 + f8*g14 + f9*g15 + f10*g16 + f11*g17 + f12*g18
                   + f13*g19 + f14*g20 + f15*g21 + f16*g22 + f17*g23 + f18*g24
                   + f19*g25;
    const float D7 = f0_*g7 + f1*g8 + f2*g9 + f3*g10 + f4*g11 + f5*g12 + f6*g13
                   + f7*g14 + f8*g15 + f9*g16 + f10*g17 + f11*g18 + f12*g19
                   + f13*g20 + f14*g21 + f15*g22 + f16*g23 + f17*g24 + f18*g25
                   + f19*g26;

    // E_j = sum_t g_{t+j}^2 via sliding window;  e_k = E_{k+s}
    const float E0 = g0*g0 + g1*g1 + g2*g2 + g3*g3 + g4*g4 + g5*g5 + g6*g6
                   + g7*g7 + g8*g8 + g9*g9 + g10*g10 + g11*g11 + g12*g12
                   + g13*g13 + g14*g14 + g15*g15 + g16*g16 + g17*g17 + g18*g18
                   + g19*g19;
    const float E1 = E0 + (g20*g20 - g0*g0);
    const float E2 = E1 + (g21*g21 - g1*g1);
    const float E3 = E2 + (g22*g22 - g2*g2);
    const float E4 = E3 + (g23*g23 - g3*g3);
    const float E5 = E4 + (g24*g24 - g4*g4);
    const float E6 = E5 + (g25*g25 - g5*g5);
    const float E7 = E6 + (g26*g26 - g6*g6);

    // select d_k = D_{k+s} with two cndmask levels (s in 0..3)
    const bool s1 = (s & 1) != 0, s2 = (s & 2) != 0;
    float d0 = s2 ? (s1 ? D3 : D2) : (s1 ? D1 : D0);
    float d1 = s2 ? (s1 ? D4 : D3) : (s1 ? D2 : D1);
    float d2 = s2 ? (s1 ? D5 : D4) : (s1 ? D3 : D2);
    float d3 = s2 ? (s1 ? D6 : D5) : (s1 ? D4 : D3);
    float d4 = s2 ? (s1 ? D7 : D6) : (s1 ? D5 : D4);
    float e0 = s2 ? (s1 ? E3 : E2) : (s1 ? E1 : E0);
    float e1 = s2 ? (s1 ? E4 : E3) : (s1 ? E2 : E1);
    float e2 = s2 ? (s1 ? E5 : E4) : (s1 ? E3 : E2);
    float e3 = s2 ? (s1 ? E6 : E5) : (s1 ? E4 : E3);
    float e4 = s2 ? (s1 ? E7 : E6) : (s1 ? E5 : E4);

    // butterfly-reduce over the 4 quarter-threads of this frame
    fn += __shfl_xor(fn, 1); fn += __shfl_xor(fn, 2);
    d0 += __shfl_xor(d0, 1); d0 += __shfl_xor(d0, 2);
    d1 += __shfl_xor(d1, 1); d1 += __shfl_xor(d1, 2);
    d2 += __shfl_xor(d2, 1); d2 += __shfl_xor(d2, 2);
    d3 += __shfl_xor(d3, 1); d3 += __shfl_xor(d3, 2);
    d4 += __shfl_xor(d4, 1); d4 += __shfl_xor(d4, 2);
    e0 += __shfl_xor(e0, 1); e0 += __shfl_xor(e0, 2);
    e1 += __shfl_xor(e1, 1); e1 += __shfl_xor(e1, 2);
    e2 += __shfl_xor(e2, 1); e2 += __shfl_xor(e2, 2);
    e3 += __shfl_xor(e3, 1); e3 += __shfl_xor(e3, 2);
    e4 += __shfl_xor(e4, 1); e4 += __shfl_xor(e4, 2);

    if (q == 0) {
        float* op = out + (long long)(b * kF + f0 + fl) * kW;
        op[0] = d0 * rsqrtf(fn * e0 + 1e-9f);
        op[1] = d1 * rsqrtf(fn * e1 + 1e-9f);
        op[2] = d2 * rsqrtf(fn * e2 + 1e-9f);
        op[3] = d3 * rsqrtf(fn * e3 + 1e-9f);
        op[4] = d4 * rsqrtf(fn * e4 + 1e-9f);
    }
}

extern "C" void kernel_launch(void* const* d_in, const int* in_sizes, int n_in,
                              void* d_out, int out_size, void* d_ws, size_t ws_size,
                              hipStream_t stream) {
    const float* x       = (const float*)d_in[0];
    const int*   periods = (const int*)d_in[1];
    float*       out     = (float*)d_out;

    const int grid = kB * BPB;   // 4032 blocks, one per (batch, 64-frame chunk)
    pitch_acorr_kernel<<<grid, 256, 0, stream>>>(x, periods, out);
}